// Round 10
// baseline (521.781 us; speedup 1.0000x reference)
//
#include <hip/hip_runtime.h>
#include <math.h>

#define N_NODES 10000
#define N_EDGES 160000
#define DIM 512
#define HDIM 256
#define EDIM 16
#define BN_EPS 1e-5f
#define L2E 1.4426950408889634f
#define LN2 0.6931471805599453f

typedef unsigned short ushort_t;
typedef unsigned int uint_t;
typedef __attribute__((ext_vector_type(8))) short bf16x8;
typedef __attribute__((ext_vector_type(4))) float f32x4;
typedef __attribute__((ext_vector_type(2))) _Float16 half2_t;
typedef __attribute__((ext_vector_type(4))) _Float16 f16x4;
typedef __attribute__((ext_vector_type(2))) unsigned int u32x2;

// ---------------- helpers ----------------
__device__ __forceinline__ ushort_t f2bf(float x) {
    uint_t u = __float_as_uint(x);
    uint_t r = (u + 0x7FFF + ((u >> 16) & 1)) >> 16;  // RNE
    return (ushort_t)r;
}
__device__ __forceinline__ float bflo(uint_t u) {
    return __uint_as_float(u << 16);
}
__device__ __forceinline__ float bfhi(uint_t u) {
    return __uint_as_float(u & 0xffff0000u);
}
__device__ __forceinline__ void gld16(const void* g, void* l) {
    __builtin_amdgcn_global_load_lds(
        (const __attribute__((address_space(1))) unsigned int*)g,
        (__attribute__((address_space(3))) unsigned int*)l, 16, 0, 0);
}
__device__ __forceinline__ half2_t u2h(uint_t u) {
    return __builtin_bit_cast(half2_t, u);
}
__device__ __forceinline__ uint_t pk_f16(float a, float b) {
    return __builtin_bit_cast(uint_t, __builtin_amdgcn_cvt_pkrtz(a, b));
}
__device__ __forceinline__ ushort_t f2h(float x) {
    return (ushort_t)(pk_f16(x, 0.f) & 0xffffu);
}
// raw HW transcendentals: v_exp_f32 (2^x), v_log_f32 (log2 x)
__device__ __forceinline__ float fexp2(float x) {
#if __has_builtin(__builtin_amdgcn_exp2f)
    return __builtin_amdgcn_exp2f(x);
#else
    return __expf(x * LN2);
#endif
}
__device__ __forceinline__ float flog2(float x) {
#if __has_builtin(__builtin_amdgcn_logf)
    return __builtin_amdgcn_logf(x);
#else
    return __logf(x) * L2E;
#endif
}
__device__ __forceinline__ void swz(int lid, int gx, int gy, int& bx, int& by) {
    int per = gy * 8;
    int grp = lid / per;
    int rem = lid - grp * per;
    int gsz = min(8, gx - grp * 8);
    by = rem / gsz;
    bx = grp * 8 + (rem - by * gsz);
}

// ---------------- CSR build ----------------
__global__ void k_hist(const int* __restrict__ dst, int* __restrict__ cnt) {
    int e = blockIdx.x * blockDim.x + threadIdx.x;
    if (e < N_EDGES) atomicAdd(&cnt[dst[e]], 1);
}

// single-pass scan: each thread owns 10 contiguous elements
__global__ __launch_bounds__(1024) void k_scan(int* __restrict__ offs, float* __restrict__ dinv) {
    __shared__ int wsum[16];
    int t = threadIdx.x, lane = t & 63, wv = t >> 6;
    int base_i = t * 10;
    int v[10];
    int s = 0;
#pragma unroll
    for (int k = 0; k < 10; k++) {
        int idx = base_i + k;
        int x = (idx < N_NODES) ? offs[idx] : 0;
        v[k] = x;
        s += x;
        if (idx < N_NODES) dinv[idx] = rsqrtf((float)x + 1.0f);
    }
    int ps = s;
#pragma unroll
    for (int off = 1; off < 64; off <<= 1) {
        int u = __shfl_up(ps, off, 64);
        if (lane >= off) ps += u;
    }
    if (lane == 63) wsum[wv] = ps;
    __syncthreads();
    if (wv == 0) {
        int w = (lane < 16) ? wsum[lane] : 0;
#pragma unroll
        for (int off = 1; off < 16; off <<= 1) {
            int u = __shfl_up(w, off, 64);
            if (lane >= off) w += u;
        }
        if (lane < 16) wsum[lane] = w;
    }
    __syncthreads();
    int wbase = (wv == 0) ? 0 : wsum[wv - 1];
    int run = wbase + ps - s;  // exclusive prefix of this thread's chunk
#pragma unroll
    for (int k = 0; k < 10; k++) {
        int idx = base_i + k;
        if (idx < N_NODES) offs[idx] = run;
        run += v[k];
    }
    if (t == 1023) offs[N_NODES] = wsum[15];
}

__global__ void k_scatter(const int* __restrict__ srcv, const int* __restrict__ dstv,
                          const float* __restrict__ ea,
                          const int* __restrict__ offs, const float* __restrict__ dinv,
                          int* __restrict__ cursor,
                          int* __restrict__ srcQ, int* __restrict__ srcH,
                          float* __restrict__ dinvArr,
                          uint_t* __restrict__ eaP) {
    int e = blockIdx.x * blockDim.x + threadIdx.x;
    if (e >= N_EDGES) return;
    int d = dstv[e];
    int p = offs[d] + atomicAdd(&cursor[d], 1);
    int s = srcv[e];
    srcQ[p] = s << 11;   // byte offset into Q (1024 f16 = 2048 B / row)
    srcH[p] = s << 9;    // byte offset into h (256 bf16 = 512 B / row)
    dinvArr[p] = dinv[s];
    const float* er = ea + (size_t)e * EDIM;
    uint_t pk[8];
#pragma unroll
    for (int k2 = 0; k2 < 8; k2++) pk[k2] = pk_f16(er[2 * k2], er[2 * k2 + 1]);
    uint_t* q = eaP + (size_t)p * 8;
    *(uint4*)q = *(uint4*)&pk[0];
    *(uint4*)(q + 4) = *(uint4*)&pk[4];
}

// ---------------- tiled transpose-convert for weights (coalesced) ----------------
__global__ __launch_bounds__(256) void k_cvtW(
    const float* __restrict__ Wf0, const float* __restrict__ Ws0,
    const float* __restrict__ Wf1, const float* __restrict__ Ws1,
    const float* __restrict__ g3W, const float* __restrict__ g4W,
    const float* __restrict__ d1W,
    ushort_t* __restrict__ W2cg0, ushort_t* __restrict__ W2cg1,
    ushort_t* __restrict__ W2g3, ushort_t* __restrict__ W2g4,
    ushort_t* __restrict__ W2d1)
{
    __shared__ ushort_t tle[64][72];
    int b = blockIdx.x, t = threadIdx.x;
    const float* src; int ldw, kin0, cin0, ldk, cout0, kout0; ushort_t* out; float scale;
    if (b < 512) {
        int layer = b >> 8, tt = b & 255;
        int g = tt >> 6, rem = tt & 63;
        int ct = rem >> 3, kt = rem & 7;
        const float* Wf = layer ? Wf1 : Wf0;
        const float* Ws = layer ? Ws1 : Ws0;
        src = (g & 1) ? Ws : Wf;
        ldw = 512; kin0 = ((g & 2) ? 512 : 0) + kt * 64; cin0 = ct * 64;
        out = layer ? W2cg1 : W2cg0; ldk = 512;
        cout0 = g * 512 + ct * 64; kout0 = kt * 64;
        scale = L2E;  // gate weights pre-scaled to exp2 domain
    } else if (b < 544) {
        int tt = b - 512; int ct = tt >> 3, kt = tt & 7;
        src = g3W; ldw = 256; kin0 = kt * 64; cin0 = ct * 64;
        out = W2g3; ldk = 512; cout0 = ct * 64; kout0 = kt * 64; scale = 1.f;
    } else if (b < 560) {
        int tt = b - 544; int ct = tt >> 2, kt = tt & 3;
        src = g4W; ldw = 256; kin0 = kt * 64; cin0 = ct * 64;
        out = W2g4; ldk = 256; cout0 = ct * 64; kout0 = kt * 64; scale = 1.f;
    } else {
        int tt = b - 560; int ct = tt >> 2, kt = tt & 3;
        src = d1W; ldw = 512; kin0 = kt * 64; cin0 = ct * 64;
        out = W2d1; ldk = 256; cout0 = ct * 64; kout0 = kt * 64; scale = 1.f;
    }
    int c = t & 63;
    int k4 = t >> 6;
#pragma unroll
    for (int i = 0; i < 16; i++) {
        int k = k4 * 16 + i;
        tle[k][c] = f2bf(src[(size_t)(kin0 + k) * ldw + cin0 + c] * scale);
    }
    __syncthreads();
    int cl = t >> 2, kq = t & 3;
    ushort_t tmp[16];
#pragma unroll
    for (int j = 0; j < 16; j++) tmp[j] = tle[kq * 16 + j][cl];
    ushort_t* dst = out + (size_t)(cout0 + cl) * ldk + kout0 + kq * 16;
    *(uint4*)dst = *(uint4*)&tmp[0];
    *(uint4*)(dst + 8) = *(uint4*)&tmp[8];
}

// ---------------- BN fold + CG bias prep ----------------
__global__ __launch_bounds__(256) void k_prep2(
    const float* __restrict__ bf0, const float* __restrict__ bs0,
    const float* __restrict__ gm0, const float* __restrict__ bt0,
    const float* __restrict__ mn0, const float* __restrict__ vr0,
    const float* __restrict__ bf1, const float* __restrict__ bs1,
    const float* __restrict__ gm1, const float* __restrict__ bt1,
    const float* __restrict__ mn1, const float* __restrict__ vr1,
    float* __restrict__ biasCG, float* __restrict__ bnS, float* __restrict__ bnB)
{
    int layer = blockIdx.x;
    const float* bf = layer ? bf1 : bf0;
    const float* bs = layer ? bs1 : bs0;
    const float* gm = layer ? gm1 : gm0;
    const float* bt = layer ? bt1 : bt0;
    const float* mn = layer ? mn1 : mn0;
    const float* vr = layer ? vr1 : vr0;
    int t = threadIdx.x;
    for (int c = t; c < 512; c += 256) {
        biasCG[layer * 1024 + c] = bf[c] * L2E;
        biasCG[layer * 1024 + 512 + c] = bs[c] * L2E;
        float rs = rsqrtf(vr[c] + BN_EPS) * gm[c];
        bnS[layer * 512 + c] = LN2 * rs;
        bnB[layer * 512 + c] = bt[c] - mn[c] * rs;
    }
}

// ---------------- mega prep: WB (A-frag W edge-part) + goalvec + cvtA ----------------
#define MP_WEP   32
#define MP_GV    40
#define MP_END   2540

__global__ __launch_bounds__(256) void k_megaprep(
    const float* __restrict__ x, const float* __restrict__ goal,
    const float* __restrict__ Wf0, const float* __restrict__ Ws0,
    const float* __restrict__ Wf1, const float* __restrict__ Ws1,
    const float* __restrict__ d1W, const float* __restrict__ d1b,
    ushort_t* __restrict__ A2, uint_t* __restrict__ WB, float* __restrict__ cgv)
{
    int b = blockIdx.x, t = threadIdx.x;
    if (b < MP_WEP) {
        // WB: per layer, 64 tiles (0..31 f-cols, 32..63 s-cols) x 64 lanes x uint2.
        // A-fragment of mfma_16x16x16f16: lane l holds W^T[m=l&15][k=(l>>4)*4+i],
        // i.e. W[1024 + (l>>4)*4 + i][tile*16 + (l&15)] * L2E as f16.
        int layer = b >> 4;
        int tt = (b & 15) * 256 + t;            // 0..4095
        int tile = tt >> 6, ln = tt & 63;
        int m = ln & 15, kq = ln >> 4;
        const float* Wsrc = (tile < 32) ? (layer ? Wf1 : Wf0) : (layer ? Ws1 : Ws0);
        int col = ((tile < 32) ? tile : tile - 32) * 16 + m;
        const float* wr = Wsrc + (size_t)(1024 + kq * 4) * 512 + col;
        uint_t u0 = pk_f16(wr[0] * L2E, wr[512] * L2E);
        uint_t u1 = pk_f16(wr[1024] * L2E, wr[1536] * L2E);
        uint_t* o = WB + (size_t)layer * 8192 + (size_t)tt * 2;
        o[0] = u0; o[1] = u1;
    } else if (b < MP_GV) {
        __shared__ float red[256];
        int bb = b - MP_WEP;
        int c = bb * 64 + (t & 63);
        int slice = t >> 6;
        float acc = 0.f;
        for (int i = 0; i < 128; i++) {
            int k = slice * 128 + i;
            acc += goal[k] * d1W[(size_t)(256 + k) * 512 + c];
        }
        red[t] = acc;
        __syncthreads();
        if (t < 128) red[t] += red[t + 128];
        __syncthreads();
        if (t < 64) cgv[c] = red[t] + red[t + 64] + d1b[c];
    } else {
        int base = ((b - MP_GV) * 256 + t) * 8;
        if (base < N_NODES * 512) {
            float4 a = *(const float4*)&x[base];
            float4 c = *(const float4*)&x[base + 4];
            uint_t o[4];
            o[0] = (uint_t)f2bf(a.x) | ((uint_t)f2bf(a.y) << 16);
            o[1] = (uint_t)f2bf(a.z) | ((uint_t)f2bf(a.w) << 16);
            o[2] = (uint_t)f2bf(c.x) | ((uint_t)f2bf(c.y) << 16);
            o[3] = (uint_t)f2bf(c.z) | ((uint_t)f2bf(c.w) << 16);
            *(uint4*)(A2 + base) = *(uint4*)&o[0];
        }
    }
}

// ---------------- bf16 MFMA GEMM, BM=128, BK=64 ----------------
// mode 1: CG (cols<1024 -> outF f32 ld 1024 + bias; cols>=1024 -> outQ interleaved f16)
__global__ __launch_bounds__(256) void k_gemm3(
    const ushort_t* __restrict__ A2, int K, int M,
    const ushort_t* __restrict__ W2t,
    float* __restrict__ outF, ushort_t* __restrict__ outQ,
    const float* __restrict__ bias, int mode, int ldc, int gx, int gy)
{
    __shared__ ushort_t As[128 * 64];
    __shared__ ushort_t Bs[128 * 64];
    int tid = threadIdx.x;
    int lane = tid & 63, w = tid >> 6;
    int wm = w & 1, wn = w >> 1;
    int lrow = lane & 15, quad = lane >> 4;
    int bx, by;
    swz(blockIdx.x, gx, gy, bx, by);
    int row0 = bx * 128, col0 = by * 128;

    f32x4 acc[4][4] = {};

    const ushort_t* ArG[4]; ushort_t* ArL[4];
    const ushort_t* BrG[4]; ushort_t* BrL[4];
#pragma unroll
    for (int p = 0; p < 4; p++) {
        int s = tid + 256 * p;
        int r = s >> 3, k8p = s & 7;
        int k8l = k8p ^ (r & 7);
        int gra = row0 + r; if (gra >= M) gra = M - 1;
        ArG[p] = A2 + (size_t)gra * K + k8l * 8;
        ArL[p] = As + s * 8;
        BrG[p] = W2t + (size_t)(col0 + r) * K + k8l * 8;
        BrL[p] = Bs + s * 8;
    }
    const ushort_t* afp[2][4];
    const ushort_t* bfp[2][4];
#pragma unroll
    for (int sl = 0; sl < 2; sl++)
#pragma unroll
        for (int mt = 0; mt < 4; mt++) {
            int r = wm * 64 + mt * 16 + lrow;
            afp[sl][mt] = As + (r * 8 + ((sl * 4 + quad) ^ (r & 7))) * 8;
            int c = wn * 64 + mt * 16 + lrow;
            bfp[sl][mt] = Bs + (c * 8 + ((sl * 4 + quad) ^ (c & 7))) * 8;
        }

    for (int k0 = 0; k0 < K; k0 += 64) {
        __syncthreads();
#pragma unroll
        for (int p = 0; p < 4; p++) {
            gld16(ArG[p] + k0, ArL[p]);
            gld16(BrG[p] + k0, BrL[p]);
        }
        __syncthreads();
#pragma unroll
        for (int sl = 0; sl < 2; sl++) {
            bf16x8 af[4], bff[4];
#pragma unroll
            for (int i = 0; i < 4; i++) {
                af[i]  = *(const bf16x8*)afp[sl][i];
                bff[i] = *(const bf16x8*)bfp[sl][i];
            }
#pragma unroll
            for (int mt = 0; mt < 4; mt++)
#pragma unroll
                for (int nt = 0; nt < 4; nt++)
                    acc[mt][nt] = __builtin_amdgcn_mfma_f32_16x16x32_bf16(
                        af[mt], bff[nt], acc[mt][nt], 0, 0, 0);
        }
    }

#pragma unroll
    for (int mt = 0; mt < 4; mt++) {
#pragma unroll
        for (int nt = 0; nt < 4; nt++) {
            int gcol = col0 + wn * 64 + nt * 16 + lrow;
#pragma unroll
            for (int r = 0; r < 4; r++) {
                int grow = row0 + wm * 64 + mt * 16 + quad * 4 + r;
                if (grow >= M) continue;
                float v = acc[mt][nt][r];
                if (mode == 1) {
                    if (gcol < 1024) {
                        outF[(size_t)grow * 1024 + gcol] = v + bias[gcol];
                    } else {
                        int c = gcol - 1024;
                        int grp = c >> 9, cc = c & 511;
                        int pos = (cc >> 1) * 4 + grp * 2 + (cc & 1);
                        outQ[(size_t)grow * 1024 + pos] = f2h(v);
                    }
                } else if (mode == 2) {
                    outF[(size_t)grow * ldc + gcol] = fmaxf(v + bias[gcol], 0.f);
                } else {
                    outQ[(size_t)grow * ldc + gcol] = f2bf(v);
                }
            }
        }
    }
}

// ---------------- bf16 MFMA GEMM, BM=64, BK=64 ----------------
// mode 3: bf16 out; mode 2: f32 relu out; mode 4: head fused with final dot
__global__ __launch_bounds__(256) void k_gemm64(
    const ushort_t* __restrict__ A2, int K, int M,
    const ushort_t* __restrict__ W2t,
    float* __restrict__ outF, ushort_t* __restrict__ outQ,
    const float* __restrict__ bias, int mode, int ldc, int gx, int gy,
    const float* __restrict__ w2v, const float* __restrict__ b2v)
{
    __shared__ ushort_t As[64 * 64];
    __shared__ ushort_t Bs[128 * 64];
    __shared__ float sOutW[4][64];
    int tid = threadIdx.x;
    int lane = tid & 63, w = tid >> 6;
    int lrow = lane & 15, quad = lane >> 4;
    int bx, by;
    swz(blockIdx.x, gx, gy, bx, by);
    int row0 = bx * 64, col0 = by * 128;

    f32x4 acc[4][2] = {};

    const ushort_t* ArG[2]; ushort_t* ArL[2];
    const ushort_t* BrG[4]; ushort_t* BrL[4];
#pragma unroll
    for (int p = 0; p < 2; p++) {
        int s = tid + 256 * p;
        int r = s >> 3, k8p = s & 7;
        int k8l = k8p ^ (r & 7);
        int gra = row0 + r; if (gra >= M) gra = M - 1;
        ArG[p] = A2 + (size_t)gra * K + k8l * 8;
        ArL[p] = As + s * 8;
    }
#pragma unroll
    for (int p = 0; p < 4; p++) {
        int s = tid + 256 * p;
        int r = s >> 3, k8p = s & 7;
        int k8l = k8p ^ (r & 7);
        BrG[p] = W2t + (size_t)(col0 + r) * K + k8l * 8;
        BrL[p] = Bs + s * 8;
    }
    const ushort_t* afp[2][4];
    const ushort_t* bfp[2][2];
#pragma unroll
    for (int sl = 0; sl < 2; sl++) {
#pragma unroll
        for (int mt = 0; mt < 4; mt++) {
            int r = mt * 16 + lrow;
            afp[sl][mt] = As + (r * 8 + ((sl * 4 + quad) ^ (r & 7))) * 8;
        }
#pragma unroll
        for (int nt = 0; nt < 2; nt++) {
            int c = w * 32 + nt * 16 + lrow;
            bfp[sl][nt] = Bs + (c * 8 + ((sl * 4 + quad) ^ (c & 7))) * 8;
        }
    }

    for (int k0 = 0; k0 < K; k0 += 64) {
        __syncthreads();
        gld16(ArG[0] + k0, ArL[0]);
        gld16(ArG[1] + k0, ArL[1]);
#pragma unroll
        for (int p = 0; p < 4; p++) gld16(BrG[p] + k0, BrL[p]);
        __syncthreads();
#pragma unroll
        for (int sl = 0; sl < 2; sl++) {
            bf16x8 af[4], bff[2];
#pragma unroll
            for (int i = 0; i < 4; i++) af[i] = *(const bf16x8*)afp[sl][i];
#pragma unroll
            for (int i = 0; i < 2; i++) bff[i] = *(const bf16x8*)bfp[sl][i];
#pragma unroll
            for (int mt = 0; mt < 4; mt++)
#pragma unroll
                for (int nt = 0; nt < 2; nt++)
                    acc[mt][nt] = __builtin_amdgcn_mfma_f32_16x16x32_bf16(
                        af[mt], bff[nt], acc[mt][nt], 0, 0, 0);
        }
    }

    if (mode == 4) {
        // fused head: out[row] += sum_cols relu(v + bias)*w2  (+ b2 once, by col0==0)
#pragma unroll
        for (int mt = 0; mt < 4; mt++) {
#pragma unroll
            for (int r = 0; r < 4; r++) {
                float p = 0.f;
#pragma unroll
                for (int nt = 0; nt < 2; nt++) {
                    int gcol = col0 + w * 32 + nt * 16 + lrow;
                    p += fmaxf(acc[mt][nt][r] + bias[gcol], 0.f) * w2v[gcol];
                }
                p += __shfl_xor(p, 1, 64);
                p += __shfl_xor(p, 2, 64);
                p += __shfl_xor(p, 4, 64);
                p += __shfl_xor(p, 8, 64);
                if (lrow == 0) sOutW[w][mt * 16 + quad * 4 + r] = p;
            }
        }
        __syncthreads();
        if (tid < 64) {
            int grow = row0 + tid;
            if (grow < M) {
                float v = sOutW[0][tid] + sOutW[1][tid] + sOutW[2][tid] + sOutW[3][tid];
                if (col0 == 0) v += b2v[0];
                atomicAdd(&outF[grow], v);
            }
        }
        return;
    }

#pragma unroll
    for (int mt = 0; mt < 4; mt++) {
#pragma unroll
        for (int nt = 0; nt < 2; nt++) {
            int gcol = col0 + w * 32 + nt * 16 + lrow;
#pragma unroll
            for (int r = 0; r < 4; r++) {
                int grow = row0 + mt * 16 + quad * 4 + r;
                if (grow >= M) continue;
                float v = acc[mt][nt][r];
                if (mode == 2) outF[(size_t)grow * ldc + gcol] = fmaxf(v + bias[gcol], 0.f);
                else outQ[(size_t)grow * ldc + gcol] = f2bf(v);
            }
        }
    }
}

// ---------------- CGConv aggregation: hybrid MFMA e·W + scalar gather ----------------
// Per block = one node (256 thr, 4 waves). Per 8-edge batch:
//  phase 1 (MFMA): EW[edge][col] = e·W, f16 into LDS (16.5 KB -> 8 blocks/CU);
//    16x16 MFMA half-wasted on edges (cheap); stores predicated es<8.
//    First-4 Q-gathers issued BEFORE this phase (addresses via broadcast srcQ
//    loads, no LDS dependency) so HBM latency hides under MFMA+pack+barrier.
//  phase 2 (scalar, r4-verified): thread t owns cols 2t,2t+1; gates =
//    P + Q + EW via fdot2 selector folds, exp2-domain nonlinearity.
#define EWSTR 1032   // f16 stride per edge row = 2064 B -> conflict-free es banks
#define CGB 8        // edge batch

#define CG_BODY(curq, jj) do {                                                     \
    uint_t ef = *(const uint_t*)&sEW[(size_t)(jj) * EWSTR + c0];                   \
    uint_t eg = *(const uint_t*)&sEW[(size_t)(jj) * EWSTR + 512 + c0];             \
    float gf0 = __builtin_amdgcn_fdot2(u2h((curq).x), SEL10, pf.x, false);         \
    float gf1 = __builtin_amdgcn_fdot2(u2h((curq).x), SEL01, pf.y, false);         \
    float gs0 = __builtin_amdgcn_fdot2(u2h((curq).y), SEL10, ps.x, false);         \
    float gs1 = __builtin_amdgcn_fdot2(u2h((curq).y), SEL01, ps.y, false);         \
    gf0 = __builtin_amdgcn_fdot2(u2h(ef), SEL10, gf0, false);                      \
    gf1 = __builtin_amdgcn_fdot2(u2h(ef), SEL01, gf1, false);                      \
    gs0 = __builtin_amdgcn_fdot2(u2h(eg), SEL10, gs0, false);                      \
    gs1 = __builtin_amdgcn_fdot2(u2h(eg), SEL01, gs1, false);                      \
    float sg0 = __builtin_amdgcn_rcpf(1.f + fexp2(-gf0));                          \
    float sg1 = __builtin_amdgcn_rcpf(1.f + fexp2(-gf1));                          \
    float sp0 = flog2(1.f + fexp2(gs0));                                           \
    float sp1 = flog2(1.f + fexp2(gs1));                                           \
    acc0 = fmaf(sg0, sp0, acc0);                                                   \
    acc1 = fmaf(sg1, sp1, acc1);                                                   \
} while (0)

__global__ __launch_bounds__(256) void k_cg_aggr(
    const float* __restrict__ xin, const float* __restrict__ P,
    const ushort_t* __restrict__ Qi,
    const uint_t* __restrict__ WB,          // layer base: 64 tiles x 64 lanes x uint2
    const float* __restrict__ bnS, const float* __restrict__ bnB,
    const int* __restrict__ offs, const int* __restrict__ srcQ,
    const uint_t* __restrict__ eaP,
    float* __restrict__ xout, ushort_t* __restrict__ A2out)
{
    const half2_t SEL10 = {(_Float16)1.f, (_Float16)0.f};
    const half2_t SEL01 = {(_Float16)0.f, (_Float16)1.f};
    __shared__ ushort_t sEW[CGB * EWSTR];   // 16.5 KB -> 8 blocks/CU
    __shared__ int sOff[12];
    int i = blockIdx.x;
    int t = threadIdx.x;
    int lane = t & 63, w = t >> 6;
    int es = lane & 15, qsel = lane >> 4;
    int c0 = 2 * t;

    // A fragments (W edge-part), 8 f-tiles + 8 s-tiles per wave, resident in VGPRs
    f16x4 wbF[8], wbS[8];
#pragma unroll
    for (int j = 0; j < 8; j++) {
        int pt = w * 8 + j;
        wbF[j] = __builtin_bit_cast(f16x4, *(const u32x2*)&WB[(size_t)pt * 128 + lane * 2]);
        wbS[j] = __builtin_bit_cast(f16x4, *(const u32x2*)&WB[(size_t)(32 + pt) * 128 + lane * 2]);
    }
    float2 pf = *(const float2*)&P[(size_t)i * 1024 + c0];
    float2 ps = *(const float2*)&P[(size_t)i * 1024 + 512 + c0];
    float acc0 = 0.f, acc1 = 0.f;
    int e0 = offs[i], e1 = offs[i + 1];
    const char* Qb = (const char*)(Qi + 4 * t);  // thread-constant base (8 B / thread)
    const char* Eb = (const char*)eaP;

    for (int base = e0; base < e1; base += CGB) {
        int g = min(CGB, e1 - base);
        __syncthreads();                       // prev batch's reads done (sEW/sOff reuse)
        if (t < 12) sOff[t] = srcQ[min(base + t, e1 - 1)];
        // early gathers for first 4 edges (broadcast address loads, no LDS dep)
        uint2 q[4];
#pragma unroll
        for (int p = 0; p < 4; p++) {
            int so = srcQ[min(base + p, e1 - 1)];
            q[p] = *(const uint2*)(Qb + (uint_t)so);
        }
        // ---- MFMA phase: EW for this batch (gathers in flight above) ----
        int ce = min(base + es, e1 - 1);
        f16x4 efr = __builtin_bit_cast(f16x4, *(const u32x2*)(Eb + (size_t)ce * 32 + qsel * 8));
#pragma unroll
        for (int j = 0; j < 8; j++) {
            f32x4 zero = {0.f, 0.f, 0.f, 0.f};
            f32x4 df = __builtin_amdgcn_mfma_f32_16x16x16f16(wbF[j], efr, zero, 0, 0, 0);
            f32x4 dv = __builtin_amdgcn_mfma_f32_16x16x16f16(wbS[j], efr, zero, 0, 0, 0);
            if (es < CGB) {
                int offf = es * EWSTR + (w * 8 + j) * 16 + qsel * 4;
                u32x2 pkf = {pk_f16(df[0], df[1]), pk_f16(df[2], df[3])};
                u32x2 pks = {pk_f16(dv[0], dv[1]), pk_f16(dv[2], dv[3])};
                *(u32x2*)&sEW[offf] = pkf;
                *(u32x2*)&sEW[offf + 512] = pks;
            }
        }
        __syncthreads();
        // ---- scalar phase: depth-4 gather pipeline (r4-verified) ----
        int j = 0;
        for (; j + 4 <= g; j += 4) {
#pragma unroll
            for (int u = 0; u < 4; u++) {
                uint2 cur = q[u];
                q[u] = *(const uint2*)(Qb + (uint_t)sOff[j + u + 4]);
                CG_BODY(cur, j + u);
            }
        }
#pragma unroll
        for (int u = 0; u < 3; u++) {
            if (j + u < g) CG_BODY(q[u], j + u);
        }
    }
    float2 s2 = *(const float2*)&bnS[c0];
    float2 b2 = *(const float2*)&bnB[c0];
    size_t ib = (size_t)i * DIM;
    float2 xi = *(const float2*)&xin[ib + c0];
    float o0 = fmaxf(xi.x + fmaf(acc0, s2.x, b2.x), 0.f);
    float o1 = fmaxf(xi.y + fmaf(acc1, s2.y, b2.y), 0.f);
    if (xout) *(float2*)&xout[ib + c0] = make_float2(o0, o1);
    ushort_t h0 = f2bf(o0), h1 = f2bf(o1);
    *(uint_t*)(A2out + (size_t)i * 512 + c0) = (uint_t)h0 | ((uint_t)h1 << 16);
}

// ---------------- GCN aggregation (batch 32, depth-8 prefetch, bf16 in/out) ----------------
__global__ __launch_bounds__(128) void k_gcn_aggr(
    const ushort_t* __restrict__ h, const float* __restrict__ dinv,
    const float* __restrict__ bias,
    const int* __restrict__ offs, const int* __restrict__ srcH,
    const float* __restrict__ dinvArr, ushort_t* __restrict__ A2out)
{
    int i = blockIdx.x;
    int t = threadIdx.x;
    int c0 = 2 * t;
    float acc0 = 0.f, acc1 = 0.f;
    int e0 = offs[i], e1 = offs[i + 1];
    __shared__ int sS[40];
    __shared__ float sD[40];
    const char* hb = (const char*)(h + c0);  // thread-constant base (4 B / thread)
    for (int base = e0; base < e1; base += 32) {
        int g = min(32, e1 - base);
        __syncthreads();
        if (t < 40) {
            bool ok = (t < g);
            sS[t] = ok ? srcH[base + t] : 0;
            sD[t] = ok ? dinvArr[base + t] : 0.f;
        }
        __syncthreads();
        uint_t q[8];
#pragma unroll
        for (int p = 0; p < 8; p++) q[p] = *(const uint_t*)(hb + (uint_t)sS[p]);
        int j = 0;
        for (; j + 8 <= g; j += 8) {
#pragma unroll
            for (int u = 0; u < 8; u++) {
                uint_t cur = q[u];
                q[u] = *(const uint_t*)(hb + (uint_t)sS[j + u + 8]);
                float d = sD[j + u];
                acc0 = fmaf(d, bflo(cur), acc0);
                acc1 = fmaf(d, bfhi(cur), acc1);
            }
        }
#pragma unroll
        for (int u = 0; u < 7; u++) {
            if (j + u < g) {
                uint_t cur = q[u];
                float d = sD[j + u];
                acc0 = fmaf(d, bflo(cur), acc0);
                acc1 = fmaf(d, bfhi(cur), acc1);
            }
        }
    }
    float di = dinv[i];
    uint_t qi = *(const uint_t*)(h + (size_t)i * HDIM + c0);
    float2 b2 = *(const float2*)&bias[c0];
    float o0 = fmaxf(di * acc0 + di * di * bflo(qi) + b2.x, 0.f);
    float o1 = fmaxf(di * acc1 + di * di * bfhi(qi) + b2.y, 0.f);
    ushort_t h0 = f2bf(o0), h1 = f2bf(o1);
    *(uint_t*)(A2out + (size_t)i * 256 + c0) = (uint_t)h0 | ((uint_t)h1 << 16);
}

// ---------------- launch ----------------
extern "C" void kernel_launch(void* const* d_in, const int* in_sizes, int n_in,
                              void* d_out, int out_size, void* d_ws, size_t ws_size,
                              hipStream_t stream) {
    (void)in_sizes; (void)n_in; (void)out_size; (void)ws_size;
    const float* x      = (const float*)d_in[0];
    const float* ea     = (const float*)d_in[1];
    const float* goal   = (const float*)d_in[2];
    const float* cgWf[2] = {(const float*)d_in[3],  (const float*)d_in[11]};
    const float* cgbf[2] = {(const float*)d_in[4],  (const float*)d_in[12]};
    const float* cgWs[2] = {(const float*)d_in[5],  (const float*)d_in[13]};
    const float* cgbs[2] = {(const float*)d_in[6],  (const float*)d_in[14]};
    const float* cggm[2] = {(const float*)d_in[7],  (const float*)d_in[15]};
    const float* cgbt[2] = {(const float*)d_in[8],  (const float*)d_in[16]};
    const float* cgmn[2] = {(const float*)d_in[9],  (const float*)d_in[17]};
    const float* cgvr[2] = {(const float*)d_in[10], (const float*)d_in[18]};
    const float* gcn3_W = (const float*)d_in[19];
    const float* gcn3_b = (const float*)d_in[20];
    const float* gcn4_W = (const float*)d_in[21];
    const float* gcn4_b = (const float*)d_in[22];
    const float* d1_W   = (const float*)d_in[23];
    const float* d1_b   = (const float*)d_in[24];
    const float* d2_W   = (const float*)d_in[25];
    const float* d2_b   = (const float*)d_in[26];
    const int*   eidx   = (const int*)d_in[27];
    const int*   srcv   = eidx;
    const int*   dstv   = eidx + N_EDGES;
    float* outp = (float*)d_out;

    // ---- workspace layout (~109 MB) ----
    char* w = (char*)d_ws;
    float*    Pbuf  = (float*)w;                      w += (size_t)N_NODES * 1024 * 4;
    ushort_t* Qbuf  = (ushort_t*)w;                   w += (size_t)N_NODES * 1024 * 2;
    float*    xB    = (float*)w;                      w += (size_t)N_NODES * 512 * 4;
    ushort_t* A2    = (ushort_t*)w;                   w += (size_t)N_NODES * 512 * 2;
    ushort_t* A3    = (ushort_t*)w;                   w += (size_t)N_NODES * 256 * 2;
    ushort_t* W2cg0 = (ushort_t*)w;                   w += (size_t)2048 * 512 * 2;
    ushort_t* W2cg1 = (ushort_t*)w;                   w += (size_t)2048 * 512 * 2;
    ushort_t* W2g3  = (ushort_t*)w;                   w += (size_t)256 * 512 * 2;
    ushort_t* W2g4  = (ushort_t*)w;                   w += (size_t)256 * 256 * 2;
    ushort_t* W2d1  = (ushort_t*)w;                   w += (size_t)512 * 256 * 2;
    uint_t*   eaP   = (uint_t*)w;                     w += (size_t)N_EDGES * 8 * 4;
    uint_t*   WB    = (uint_t*)w;                     w += 16384 * 4;
    float*    cgv   = (float*)w;                      w += 512 * 4;
    float*    biasCG = (float*)w;                     w += 2048 * 4;
    float*    bnS    = (float*)w;                     w += 1024 * 4;
    float*    bnB    = (float*)w;                     w += 1024 * 4;
    int*      srcQ    = (int*)w;                      w += N_EDGES * 4;
    int*      srcH    = (int*)w;                      w += N_EDGES * 4;
    float*    dinvArr = (float*)w;                    w += N_EDGES * 4;
    int*      offs    = (int*)w;                      w += (N_NODES + 1) * 4;
    int*      cursor  = (int*)w;                      w += N_NODES * 4;
    float*    dinv    = (float*)w;                    w += N_NODES * 4;
    ushort_t* h3 = (ushort_t*)Pbuf;          // N x 256 bf16

    // ---- prep ----
    k_cvtW<<<592, 256, 0, stream>>>(cgWf[0], cgWs[0], cgWf[1], cgWs[1],
                                    gcn3_W, gcn4_W, d1_W,
                                    W2cg0, W2cg1, W2g3, W2g4, W2d1);
    k_prep2<<<2, 256, 0, stream>>>(cgbf[0], cgbs[0], cggm[0], cgbt[0], cgmn[0], cgvr[0],
                                   cgbf[1], cgbs[1], cggm[1], cgbt[1], cgmn[1], cgvr[1],
                                   biasCG, bnS, bnB);
    k_megaprep<<<MP_END, 256, 0, stream>>>(x, goal,
        cgWf[0], cgWs[0], cgWf[1], cgWs[1], d1_W, d1_b, A2, WB, cgv);

    // ---- CSR build ----
    hipMemsetAsync(offs, 0, (N_NODES + 1) * sizeof(int), stream);
    hipMemsetAsync(cursor, 0, N_NODES * sizeof(int), stream);
    k_hist<<<(N_EDGES + 255) / 256, 256, 0, stream>>>(dstv, offs);
    k_scan<<<1, 1024, 0, stream>>>(offs, dinv);
    k_scatter<<<(N_EDGES + 255) / 256, 256, 0, stream>>>(srcv, dstv, ea, offs, dinv,
                                                         cursor, srcQ, srcH, dinvArr, eaP);

    // ---- CG layer 1 ----
    k_gemm3<<<79 * 16, 256, 0, stream>>>(A2, 512, N_NODES, W2cg0,
                                         Pbuf, Qbuf, biasCG, 1, 0, 79, 16);
    k_cg_aggr<<<N_NODES, 256, 0, stream>>>(x, Pbuf, Qbuf, WB,
                                           bnS, bnB, offs, srcQ, eaP, xB, A2);
    // ---- CG layer 2 (fp32 xout not needed downstream) ----
    k_gemm3<<<79 * 16, 256, 0, stream>>>(A2, 512, N_NODES, W2cg1,
                                         Pbuf, Qbuf, biasCG + 1024, 1, 0, 79, 16);
    k_cg_aggr<<<N_NODES, 256, 0, stream>>>(xB, Pbuf, Qbuf, WB + 8192,
                                           bnS + 512, bnB + 512, offs, srcQ, eaP,
                                           nullptr, A2);

    // ---- GCN 3: 512 -> 256 ----
    k_gemm64<<<157 * 2, 256, 0, stream>>>(A2, 512, N_NODES, W2g3,
                                          nullptr, h3, nullptr, 3, HDIM, 157, 2,
                                          nullptr, nullptr);
    k_gcn_aggr<<<N_NODES, 128, 0, stream>>>(h3, dinv, gcn3_b, offs, srcH, dinvArr, A3);

    // ---- GCN 4: 256 -> 256 ----
    k_gemm64<<<157 * 2, 256, 0, stream>>>(A3, 256, N_NODES, W2g4,
                                          nullptr, h3, nullptr, 3, HDIM, 157, 2,
                                          nullptr, nullptr);
    k_gcn_aggr<<<N_NODES, 128, 0, stream>>>(h3, dinv, gcn4_b, offs, srcH, dinvArr, A3);

    // ---- dense head fused with final dot ----
    hipMemsetAsync(outp, 0, N_NODES * sizeof(float), stream);
    k_gemm64<<<157 * 4, 256, 0, stream>>>(A3, 256, N_NODES, W2d1,
                                          outp, nullptr, cgv, 4, DIM, 157, 4,
                                          d2_W, d2_b);
}

// Round 11
// 502.194 us; speedup vs baseline: 1.0390x; 1.0390x over previous
//
#include <hip/hip_runtime.h>
#include <math.h>

#define N_NODES 10000
#define N_EDGES 160000
#define DIM 512
#define HDIM 256
#define EDIM 16
#define BN_EPS 1e-5f
#define L2E 1.4426950408889634f
#define LN2 0.6931471805599453f

typedef unsigned short ushort_t;
typedef unsigned int uint_t;
typedef __attribute__((ext_vector_type(8))) short bf16x8;
typedef __attribute__((ext_vector_type(4))) float f32x4;
typedef __attribute__((ext_vector_type(2))) _Float16 half2_t;
typedef __attribute__((ext_vector_type(4))) _Float16 f16x4;
typedef __attribute__((ext_vector_type(2))) unsigned int u32x2;

// ---------------- helpers ----------------
__device__ __forceinline__ ushort_t f2bf(float x) {
    uint_t u = __float_as_uint(x);
    uint_t r = (u + 0x7FFF + ((u >> 16) & 1)) >> 16;  // RNE
    return (ushort_t)r;
}
__device__ __forceinline__ float bflo(uint_t u) {
    return __uint_as_float(u << 16);
}
__device__ __forceinline__ float bfhi(uint_t u) {
    return __uint_as_float(u & 0xffff0000u);
}
__device__ __forceinline__ void gld16(const void* g, void* l) {
    __builtin_amdgcn_global_load_lds(
        (const __attribute__((address_space(1))) unsigned int*)g,
        (__attribute__((address_space(3))) unsigned int*)l, 16, 0, 0);
}
__device__ __forceinline__ half2_t u2h(uint_t u) {
    return __builtin_bit_cast(half2_t, u);
}
__device__ __forceinline__ uint_t pk_f16(float a, float b) {
    return __builtin_bit_cast(uint_t, __builtin_amdgcn_cvt_pkrtz(a, b));
}
__device__ __forceinline__ ushort_t f2h(float x) {
    return (ushort_t)(pk_f16(x, 0.f) & 0xffffu);
}
// raw HW transcendentals: v_exp_f32 (2^x), v_log_f32 (log2 x)
__device__ __forceinline__ float fexp2(float x) {
#if __has_builtin(__builtin_amdgcn_exp2f)
    return __builtin_amdgcn_exp2f(x);
#else
    return __expf(x * LN2);
#endif
}
__device__ __forceinline__ float flog2(float x) {
#if __has_builtin(__builtin_amdgcn_logf)
    return __builtin_amdgcn_logf(x);
#else
    return __logf(x) * L2E;
#endif
}
__device__ __forceinline__ void swz(int lid, int gx, int gy, int& bx, int& by) {
    int per = gy * 8;
    int grp = lid / per;
    int rem = lid - grp * per;
    int gsz = min(8, gx - grp * 8);
    by = rem / gsz;
    bx = grp * 8 + (rem - by * gsz);
}

// ---------------- CSR build ----------------
__global__ void k_hist(const int* __restrict__ dst, int* __restrict__ cnt) {
    int e = blockIdx.x * blockDim.x + threadIdx.x;
    if (e < N_EDGES) atomicAdd(&cnt[dst[e]], 1);
}

// single-pass scan: each thread owns 10 contiguous elements
__global__ __launch_bounds__(1024) void k_scan(int* __restrict__ offs, float* __restrict__ dinv) {
    __shared__ int wsum[16];
    int t = threadIdx.x, lane = t & 63, wv = t >> 6;
    int base_i = t * 10;
    int v[10];
    int s = 0;
#pragma unroll
    for (int k = 0; k < 10; k++) {
        int idx = base_i + k;
        int x = (idx < N_NODES) ? offs[idx] : 0;
        v[k] = x;
        s += x;
        if (idx < N_NODES) dinv[idx] = rsqrtf((float)x + 1.0f);
    }
    int ps = s;
#pragma unroll
    for (int off = 1; off < 64; off <<= 1) {
        int u = __shfl_up(ps, off, 64);
        if (lane >= off) ps += u;
    }
    if (lane == 63) wsum[wv] = ps;
    __syncthreads();
    if (wv == 0) {
        int w = (lane < 16) ? wsum[lane] : 0;
#pragma unroll
        for (int off = 1; off < 16; off <<= 1) {
            int u = __shfl_up(w, off, 64);
            if (lane >= off) w += u;
        }
        if (lane < 16) wsum[lane] = w;
    }
    __syncthreads();
    int wbase = (wv == 0) ? 0 : wsum[wv - 1];
    int run = wbase + ps - s;  // exclusive prefix of this thread's chunk
#pragma unroll
    for (int k = 0; k < 10; k++) {
        int idx = base_i + k;
        if (idx < N_NODES) offs[idx] = run;
        run += v[k];
    }
    if (t == 1023) offs[N_NODES] = wsum[15];
}

__global__ void k_scatter(const int* __restrict__ srcv, const int* __restrict__ dstv,
                          const float* __restrict__ ea,
                          const int* __restrict__ offs, const float* __restrict__ dinv,
                          int* __restrict__ cursor,
                          int* __restrict__ srcQ, int* __restrict__ srcH,
                          float* __restrict__ dinvArr,
                          uint_t* __restrict__ eaP) {
    int e = blockIdx.x * blockDim.x + threadIdx.x;
    if (e >= N_EDGES) return;
    int d = dstv[e];
    int p = offs[d] + atomicAdd(&cursor[d], 1);
    int s = srcv[e];
    srcQ[p] = s << 11;   // byte offset into Q (1024 f16 = 2048 B / row)
    srcH[p] = s << 9;    // byte offset into h (256 bf16 = 512 B / row)
    dinvArr[p] = dinv[s];
    const float* er = ea + (size_t)e * EDIM;
    uint_t pk[8];
#pragma unroll
    for (int k2 = 0; k2 < 8; k2++) pk[k2] = pk_f16(er[2 * k2], er[2 * k2 + 1]);
    uint_t* q = eaP + (size_t)p * 8;
    *(uint4*)q = *(uint4*)&pk[0];
    *(uint4*)(q + 4) = *(uint4*)&pk[4];
}

// ---------------- tiled transpose-convert for weights (coalesced) ----------------
__global__ __launch_bounds__(256) void k_cvtW(
    const float* __restrict__ Wf0, const float* __restrict__ Ws0,
    const float* __restrict__ Wf1, const float* __restrict__ Ws1,
    const float* __restrict__ g3W, const float* __restrict__ g4W,
    const float* __restrict__ d1W,
    ushort_t* __restrict__ W2cg0, ushort_t* __restrict__ W2cg1,
    ushort_t* __restrict__ W2g3, ushort_t* __restrict__ W2g4,
    ushort_t* __restrict__ W2d1)
{
    __shared__ ushort_t tle[64][72];
    int b = blockIdx.x, t = threadIdx.x;
    const float* src; int ldw, kin0, cin0, ldk, cout0, kout0; ushort_t* out; float scale;
    if (b < 512) {
        int layer = b >> 8, tt = b & 255;
        int g = tt >> 6, rem = tt & 63;
        int ct = rem >> 3, kt = rem & 7;
        const float* Wf = layer ? Wf1 : Wf0;
        const float* Ws = layer ? Ws1 : Ws0;
        src = (g & 1) ? Ws : Wf;
        ldw = 512; kin0 = ((g & 2) ? 512 : 0) + kt * 64; cin0 = ct * 64;
        out = layer ? W2cg1 : W2cg0; ldk = 512;
        cout0 = g * 512 + ct * 64; kout0 = kt * 64;
        scale = L2E;  // gate weights pre-scaled to exp2 domain
    } else if (b < 544) {
        int tt = b - 512; int ct = tt >> 3, kt = tt & 7;
        src = g3W; ldw = 256; kin0 = kt * 64; cin0 = ct * 64;
        out = W2g3; ldk = 512; cout0 = ct * 64; kout0 = kt * 64; scale = 1.f;
    } else if (b < 560) {
        int tt = b - 544; int ct = tt >> 2, kt = tt & 3;
        src = g4W; ldw = 256; kin0 = kt * 64; cin0 = ct * 64;
        out = W2g4; ldk = 256; cout0 = ct * 64; kout0 = kt * 64; scale = 1.f;
    } else {
        int tt = b - 560; int ct = tt >> 2, kt = tt & 3;
        src = d1W; ldw = 512; kin0 = kt * 64; cin0 = ct * 64;
        out = W2d1; ldk = 256; cout0 = ct * 64; kout0 = kt * 64; scale = 1.f;
    }
    int c = t & 63;
    int k4 = t >> 6;
#pragma unroll
    for (int i = 0; i < 16; i++) {
        int k = k4 * 16 + i;
        tle[k][c] = f2bf(src[(size_t)(kin0 + k) * ldw + cin0 + c] * scale);
    }
    __syncthreads();
    int cl = t >> 2, kq = t & 3;
    ushort_t tmp[16];
#pragma unroll
    for (int j = 0; j < 16; j++) tmp[j] = tle[kq * 16 + j][cl];
    ushort_t* dst = out + (size_t)(cout0 + cl) * ldk + kout0 + kq * 16;
    *(uint4*)dst = *(uint4*)&tmp[0];
    *(uint4*)(dst + 8) = *(uint4*)&tmp[8];
}

// ---------------- BN fold + CG bias prep ----------------
__global__ __launch_bounds__(256) void k_prep2(
    const float* __restrict__ bf0, const float* __restrict__ bs0,
    const float* __restrict__ gm0, const float* __restrict__ bt0,
    const float* __restrict__ mn0, const float* __restrict__ vr0,
    const float* __restrict__ bf1, const float* __restrict__ bs1,
    const float* __restrict__ gm1, const float* __restrict__ bt1,
    const float* __restrict__ mn1, const float* __restrict__ vr1,
    float* __restrict__ biasCG, float* __restrict__ bnS, float* __restrict__ bnB)
{
    int layer = blockIdx.x;
    const float* bf = layer ? bf1 : bf0;
    const float* bs = layer ? bs1 : bs0;
    const float* gm = layer ? gm1 : gm0;
    const float* bt = layer ? bt1 : bt0;
    const float* mn = layer ? mn1 : mn0;
    const float* vr = layer ? vr1 : vr0;
    int t = threadIdx.x;
    for (int c = t; c < 512; c += 256) {
        biasCG[layer * 1024 + c] = bf[c] * L2E;
        biasCG[layer * 1024 + 512 + c] = bs[c] * L2E;
        float rs = rsqrtf(vr[c] + BN_EPS) * gm[c];
        bnS[layer * 512 + c] = LN2 * rs;
        bnB[layer * 512 + c] = bt[c] - mn[c] * rs;
    }
}

// ---------------- mega prep: WB (A-frag W edge-part) + goalvec + cvtA ----------------
#define MP_WEP   32
#define MP_GV    40
#define MP_END   2540

__global__ __launch_bounds__(256) void k_megaprep(
    const float* __restrict__ x, const float* __restrict__ goal,
    const float* __restrict__ Wf0, const float* __restrict__ Ws0,
    const float* __restrict__ Wf1, const float* __restrict__ Ws1,
    const float* __restrict__ d1W, const float* __restrict__ d1b,
    ushort_t* __restrict__ A2, uint_t* __restrict__ WB, float* __restrict__ cgv)
{
    int b = blockIdx.x, t = threadIdx.x;
    if (b < MP_WEP) {
        // WB: per layer, 64 tiles (0..31 f-cols, 32..63 s-cols) x 64 lanes x uint2.
        // A-fragment of mfma_16x16x16f16: lane l holds W^T[m=l&15][k=(l>>4)*4+i],
        // i.e. W[1024 + (l>>4)*4 + i][tile*16 + (l&15)] * L2E as f16.
        int layer = b >> 4;
        int tt = (b & 15) * 256 + t;            // 0..4095
        int tile = tt >> 6, ln = tt & 63;
        int m = ln & 15, kq = ln >> 4;
        const float* Wsrc = (tile < 32) ? (layer ? Wf1 : Wf0) : (layer ? Ws1 : Ws0);
        int col = ((tile < 32) ? tile : tile - 32) * 16 + m;
        const float* wr = Wsrc + (size_t)(1024 + kq * 4) * 512 + col;
        uint_t u0 = pk_f16(wr[0] * L2E, wr[512] * L2E);
        uint_t u1 = pk_f16(wr[1024] * L2E, wr[1536] * L2E);
        uint_t* o = WB + (size_t)layer * 8192 + (size_t)tt * 2;
        o[0] = u0; o[1] = u1;
    } else if (b < MP_GV) {
        __shared__ float red[256];
        int bb = b - MP_WEP;
        int c = bb * 64 + (t & 63);
        int slice = t >> 6;
        float acc = 0.f;
        for (int i = 0; i < 128; i++) {
            int k = slice * 128 + i;
            acc += goal[k] * d1W[(size_t)(256 + k) * 512 + c];
        }
        red[t] = acc;
        __syncthreads();
        if (t < 128) red[t] += red[t + 128];
        __syncthreads();
        if (t < 64) cgv[c] = red[t] + red[t + 64] + d1b[c];
    } else {
        int base = ((b - MP_GV) * 256 + t) * 8;
        if (base < N_NODES * 512) {
            float4 a = *(const float4*)&x[base];
            float4 c = *(const float4*)&x[base + 4];
            uint_t o[4];
            o[0] = (uint_t)f2bf(a.x) | ((uint_t)f2bf(a.y) << 16);
            o[1] = (uint_t)f2bf(a.z) | ((uint_t)f2bf(a.w) << 16);
            o[2] = (uint_t)f2bf(c.x) | ((uint_t)f2bf(c.y) << 16);
            o[3] = (uint_t)f2bf(c.z) | ((uint_t)f2bf(c.w) << 16);
            *(uint4*)(A2 + base) = *(uint4*)&o[0];
        }
    }
}

// ---------------- bf16 MFMA GEMM, BM=128, BK=64 ----------------
// mode 1: CG (cols<1024 -> outF f32 ld 1024 + bias; cols>=1024 -> outQ interleaved f16)
__global__ __launch_bounds__(256) void k_gemm3(
    const ushort_t* __restrict__ A2, int K, int M,
    const ushort_t* __restrict__ W2t,
    float* __restrict__ outF, ushort_t* __restrict__ outQ,
    const float* __restrict__ bias, int mode, int ldc, int gx, int gy)
{
    __shared__ ushort_t As[128 * 64];
    __shared__ ushort_t Bs[128 * 64];
    int tid = threadIdx.x;
    int lane = tid & 63, w = tid >> 6;
    int wm = w & 1, wn = w >> 1;
    int lrow = lane & 15, quad = lane >> 4;
    int bx, by;
    swz(blockIdx.x, gx, gy, bx, by);
    int row0 = bx * 128, col0 = by * 128;

    f32x4 acc[4][4] = {};

    const ushort_t* ArG[4]; ushort_t* ArL[4];
    const ushort_t* BrG[4]; ushort_t* BrL[4];
#pragma unroll
    for (int p = 0; p < 4; p++) {
        int s = tid + 256 * p;
        int r = s >> 3, k8p = s & 7;
        int k8l = k8p ^ (r & 7);
        int gra = row0 + r; if (gra >= M) gra = M - 1;
        ArG[p] = A2 + (size_t)gra * K + k8l * 8;
        ArL[p] = As + s * 8;
        BrG[p] = W2t + (size_t)(col0 + r) * K + k8l * 8;
        BrL[p] = Bs + s * 8;
    }
    const ushort_t* afp[2][4];
    const ushort_t* bfp[2][4];
#pragma unroll
    for (int sl = 0; sl < 2; sl++)
#pragma unroll
        for (int mt = 0; mt < 4; mt++) {
            int r = wm * 64 + mt * 16 + lrow;
            afp[sl][mt] = As + (r * 8 + ((sl * 4 + quad) ^ (r & 7))) * 8;
            int c = wn * 64 + mt * 16 + lrow;
            bfp[sl][mt] = Bs + (c * 8 + ((sl * 4 + quad) ^ (c & 7))) * 8;
        }

    for (int k0 = 0; k0 < K; k0 += 64) {
        __syncthreads();
#pragma unroll
        for (int p = 0; p < 4; p++) {
            gld16(ArG[p] + k0, ArL[p]);
            gld16(BrG[p] + k0, BrL[p]);
        }
        __syncthreads();
#pragma unroll
        for (int sl = 0; sl < 2; sl++) {
            bf16x8 af[4], bff[4];
#pragma unroll
            for (int i = 0; i < 4; i++) {
                af[i]  = *(const bf16x8*)afp[sl][i];
                bff[i] = *(const bf16x8*)bfp[sl][i];
            }
#pragma unroll
            for (int mt = 0; mt < 4; mt++)
#pragma unroll
                for (int nt = 0; nt < 4; nt++)
                    acc[mt][nt] = __builtin_amdgcn_mfma_f32_16x16x32_bf16(
                        af[mt], bff[nt], acc[mt][nt], 0, 0, 0);
        }
    }

#pragma unroll
    for (int mt = 0; mt < 4; mt++) {
#pragma unroll
        for (int nt = 0; nt < 4; nt++) {
            int gcol = col0 + wn * 64 + nt * 16 + lrow;
#pragma unroll
            for (int r = 0; r < 4; r++) {
                int grow = row0 + wm * 64 + mt * 16 + quad * 4 + r;
                if (grow >= M) continue;
                float v = acc[mt][nt][r];
                if (mode == 1) {
                    if (gcol < 1024) {
                        outF[(size_t)grow * 1024 + gcol] = v + bias[gcol];
                    } else {
                        int c = gcol - 1024;
                        int grp = c >> 9, cc = c & 511;
                        int pos = (cc >> 1) * 4 + grp * 2 + (cc & 1);
                        outQ[(size_t)grow * 1024 + pos] = f2h(v);
                    }
                } else if (mode == 2) {
                    outF[(size_t)grow * ldc + gcol] = fmaxf(v + bias[gcol], 0.f);
                } else {
                    outQ[(size_t)grow * ldc + gcol] = f2bf(v);
                }
            }
        }
    }
}

// ---------------- bf16 MFMA GEMM, BM=64, BK=64 ----------------
// mode 3: bf16 out; mode 2: f32 relu out; mode 4: head fused with final dot
__global__ __launch_bounds__(256) void k_gemm64(
    const ushort_t* __restrict__ A2, int K, int M,
    const ushort_t* __restrict__ W2t,
    float* __restrict__ outF, ushort_t* __restrict__ outQ,
    const float* __restrict__ bias, int mode, int ldc, int gx, int gy,
    const float* __restrict__ w2v, const float* __restrict__ b2v)
{
    __shared__ ushort_t As[64 * 64];
    __shared__ ushort_t Bs[128 * 64];
    __shared__ float sOutW[4][64];
    int tid = threadIdx.x;
    int lane = tid & 63, w = tid >> 6;
    int lrow = lane & 15, quad = lane >> 4;
    int bx, by;
    swz(blockIdx.x, gx, gy, bx, by);
    int row0 = bx * 64, col0 = by * 128;

    f32x4 acc[4][2] = {};

    const ushort_t* ArG[2]; ushort_t* ArL[2];
    const ushort_t* BrG[4]; ushort_t* BrL[4];
#pragma unroll
    for (int p = 0; p < 2; p++) {
        int s = tid + 256 * p;
        int r = s >> 3, k8p = s & 7;
        int k8l = k8p ^ (r & 7);
        int gra = row0 + r; if (gra >= M) gra = M - 1;
        ArG[p] = A2 + (size_t)gra * K + k8l * 8;
        ArL[p] = As + s * 8;
    }
#pragma unroll
    for (int p = 0; p < 4; p++) {
        int s = tid + 256 * p;
        int r = s >> 3, k8p = s & 7;
        int k8l = k8p ^ (r & 7);
        BrG[p] = W2t + (size_t)(col0 + r) * K + k8l * 8;
        BrL[p] = Bs + s * 8;
    }
    const ushort_t* afp[2][4];
    const ushort_t* bfp[2][2];
#pragma unroll
    for (int sl = 0; sl < 2; sl++) {
#pragma unroll
        for (int mt = 0; mt < 4; mt++) {
            int r = mt * 16 + lrow;
            afp[sl][mt] = As + (r * 8 + ((sl * 4 + quad) ^ (r & 7))) * 8;
        }
#pragma unroll
        for (int nt = 0; nt < 2; nt++) {
            int c = w * 32 + nt * 16 + lrow;
            bfp[sl][nt] = Bs + (c * 8 + ((sl * 4 + quad) ^ (c & 7))) * 8;
        }
    }

    for (int k0 = 0; k0 < K; k0 += 64) {
        __syncthreads();
        gld16(ArG[0] + k0, ArL[0]);
        gld16(ArG[1] + k0, ArL[1]);
#pragma unroll
        for (int p = 0; p < 4; p++) gld16(BrG[p] + k0, BrL[p]);
        __syncthreads();
#pragma unroll
        for (int sl = 0; sl < 2; sl++) {
            bf16x8 af[4], bff[2];
#pragma unroll
            for (int i = 0; i < 4; i++) af[i] = *(const bf16x8*)afp[sl][i];
#pragma unroll
            for (int i = 0; i < 2; i++) bff[i] = *(const bf16x8*)bfp[sl][i];
#pragma unroll
            for (int mt = 0; mt < 4; mt++)
#pragma unroll
                for (int nt = 0; nt < 2; nt++)
                    acc[mt][nt] = __builtin_amdgcn_mfma_f32_16x16x32_bf16(
                        af[mt], bff[nt], acc[mt][nt], 0, 0, 0);
        }
    }

    if (mode == 4) {
        // fused head: out[row] += sum_cols relu(v + bias)*w2  (+ b2 once, by col0==0)
#pragma unroll
        for (int mt = 0; mt < 4; mt++) {
#pragma unroll
            for (int r = 0; r < 4; r++) {
                float p = 0.f;
#pragma unroll
                for (int nt = 0; nt < 2; nt++) {
                    int gcol = col0 + w * 32 + nt * 16 + lrow;
                    p += fmaxf(acc[mt][nt][r] + bias[gcol], 0.f) * w2v[gcol];
                }
                p += __shfl_xor(p, 1, 64);
                p += __shfl_xor(p, 2, 64);
                p += __shfl_xor(p, 4, 64);
                p += __shfl_xor(p, 8, 64);
                if (lrow == 0) sOutW[w][mt * 16 + quad * 4 + r] = p;
            }
        }
        __syncthreads();
        if (tid < 64) {
            int grow = row0 + tid;
            if (grow < M) {
                float v = sOutW[0][tid] + sOutW[1][tid] + sOutW[2][tid] + sOutW[3][tid];
                if (col0 == 0) v += b2v[0];
                atomicAdd(&outF[grow], v);
            }
        }
        return;
    }

#pragma unroll
    for (int mt = 0; mt < 4; mt++) {
#pragma unroll
        for (int nt = 0; nt < 2; nt++) {
            int gcol = col0 + w * 32 + nt * 16 + lrow;
#pragma unroll
            for (int r = 0; r < 4; r++) {
                int grow = row0 + mt * 16 + quad * 4 + r;
                if (grow >= M) continue;
                float v = acc[mt][nt][r];
                if (mode == 2) outF[(size_t)grow * ldc + gcol] = fmaxf(v + bias[gcol], 0.f);
                else outQ[(size_t)grow * ldc + gcol] = f2bf(v);
            }
        }
    }
}

// ---------------- CGConv aggregation: hybrid MFMA e·W + scalar gather ----------------
// Per block = one node (256 thr, 4 waves). Per 16-edge batch:
//  phase 1 (MFMA): EW[edge][col] = e·W, f16 into LDS. Layout: per edge a 2048 B row
//    [f:1024|s:1024] of 8 B blocks with physical block = (col>>2) ^ edge. Write banks
//    2*((b0^es)&15) cover all banks evenly (0 conflicts); reads are 2-way (free).
//    First-4 Q-gathers issued BEFORE this phase (uniform srcQ loads, no LDS dep).
//  phase 2 (scalar, r4-verified): thread t owns cols 2t,2t+1; gates =
//    P + Q + EW via fdot2 selector folds, exp2-domain nonlinearity.
#define CG_BODY(curq, jj) do {                                                     \
    int ebo = ((jj) << 11) + (((blkb ^ (jj)) << 3) | lo2);                         \
    uint_t ef = *(const uint_t*)(ewb + ebo);                                       \
    uint_t eg = *(const uint_t*)(ewb + ebo + 1024);                                \
    float gf0 = __builtin_amdgcn_fdot2(u2h((curq).x), SEL10, pf.x, false);         \
    float gf1 = __builtin_amdgcn_fdot2(u2h((curq).x), SEL01, pf.y, false);         \
    float gs0 = __builtin_amdgcn_fdot2(u2h((curq).y), SEL10, ps.x, false);         \
    float gs1 = __builtin_amdgcn_fdot2(u2h((curq).y), SEL01, ps.y, false);         \
    gf0 = __builtin_amdgcn_fdot2(u2h(ef), SEL10, gf0, false);                      \
    gf1 = __builtin_amdgcn_fdot2(u2h(ef), SEL01, gf1, false);                      \
    gs0 = __builtin_amdgcn_fdot2(u2h(eg), SEL10, gs0, false);                      \
    gs1 = __builtin_amdgcn_fdot2(u2h(eg), SEL01, gs1, false);                      \
    float sg0 = __builtin_amdgcn_rcpf(1.f + fexp2(-gf0));                          \
    float sg1 = __builtin_amdgcn_rcpf(1.f + fexp2(-gf1));                          \
    float sp0 = flog2(1.f + fexp2(gs0));                                           \
    float sp1 = flog2(1.f + fexp2(gs1));                                           \
    acc0 = fmaf(sg0, sp0, acc0);                                                   \
    acc1 = fmaf(sg1, sp1, acc1);                                                   \
} while (0)

__global__ __launch_bounds__(256) void k_cg_aggr(
    const float* __restrict__ xin, const float* __restrict__ P,
    const ushort_t* __restrict__ Qi,
    const uint_t* __restrict__ WB,          // layer base: 64 tiles x 64 lanes x uint2
    const float* __restrict__ bnS, const float* __restrict__ bnB,
    const int* __restrict__ offs, const int* __restrict__ srcQ,
    const uint_t* __restrict__ eaP,
    float* __restrict__ xout, ushort_t* __restrict__ A2out)
{
    const half2_t SEL10 = {(_Float16)1.f, (_Float16)0.f};
    const half2_t SEL01 = {(_Float16)0.f, (_Float16)1.f};
    __shared__ ushort_t sEW[16 * 1024];     // 32 KB: 16 edges x 2048 B (XOR-swizzled)
    __shared__ int sOff[20];
    char* ewb = (char*)sEW;
    int i = blockIdx.x;
    int t = threadIdx.x;
    int lane = t & 63, w = t >> 6;
    int es = lane & 15, qsel = lane >> 4;
    int c0 = 2 * t;
    int blkb = c0 >> 2;            // block index of this thread's col pair
    int lo2 = (c0 & 3) * 2;        // byte offset within 8B block (0 or 4)

    // A fragments (W edge-part), 8 f-tiles + 8 s-tiles per wave, resident in VGPRs
    f16x4 wbF[8], wbS[8];
#pragma unroll
    for (int j = 0; j < 8; j++) {
        int pt = w * 8 + j;
        wbF[j] = __builtin_bit_cast(f16x4, *(const u32x2*)&WB[(size_t)pt * 128 + lane * 2]);
        wbS[j] = __builtin_bit_cast(f16x4, *(const u32x2*)&WB[(size_t)(32 + pt) * 128 + lane * 2]);
    }
    float2 pf = *(const float2*)&P[(size_t)i * 1024 + c0];
    float2 ps = *(const float2*)&P[(size_t)i * 1024 + 512 + c0];
    float acc0 = 0.f, acc1 = 0.f;
    int e0 = offs[i], e1 = offs[i + 1];
    const char* Qb = (const char*)(Qi + 4 * t);  // thread-constant base (8 B / thread)
    const char* Eb = (const char*)eaP;

    for (int base = e0; base < e1; base += 16) {
        int g = min(16, e1 - base);
        __syncthreads();                       // prev batch's reads done (sEW/sOff reuse)
        if (t < 20) sOff[t] = srcQ[min(base + t, e1 - 1)];
        // early gathers for first 4 edges (uniform address loads, no LDS dep)
        uint2 q[4];
#pragma unroll
        for (int p = 0; p < 4; p++) {
            int so = srcQ[min(base + p, e1 - 1)];
            q[p] = *(const uint2*)(Qb + (uint_t)so);
        }
        // ---- MFMA phase: EW for this batch (gathers in flight above) ----
        int ce = min(base + es, e1 - 1);
        f16x4 efr = __builtin_bit_cast(f16x4, *(const u32x2*)(Eb + (size_t)ce * 32 + qsel * 8));
#pragma unroll
        for (int j = 0; j < 8; j++) {
            f32x4 zero = {0.f, 0.f, 0.f, 0.f};
            f32x4 df = __builtin_amdgcn_mfma_f32_16x16x16f16(wbF[j], efr, zero, 0, 0, 0);
            f32x4 dv = __builtin_amdgcn_mfma_f32_16x16x16f16(wbS[j], efr, zero, 0, 0, 0);
            int b0 = (w * 8 + j) * 4 + qsel;
            char* p = ewb + es * 2048 + ((b0 ^ es) << 3);
            u32x2 pkf = {pk_f16(df[0], df[1]), pk_f16(df[2], df[3])};
            u32x2 pks = {pk_f16(dv[0], dv[1]), pk_f16(dv[2], dv[3])};
            *(u32x2*)p = pkf;
            *(u32x2*)(p + 1024) = pks;
        }
        __syncthreads();
        // ---- scalar phase: depth-4 gather pipeline (r4-verified) ----
        int j = 0;
        for (; j + 4 <= g; j += 4) {
#pragma unroll
            for (int u = 0; u < 4; u++) {
                uint2 cur = q[u];
                q[u] = *(const uint2*)(Qb + (uint_t)sOff[j + u + 4]);
                CG_BODY(cur, j + u);
            }
        }
#pragma unroll
        for (int u = 0; u < 3; u++) {
            if (j + u < g) CG_BODY(q[u], j + u);
        }
    }
    float2 s2 = *(const float2*)&bnS[c0];
    float2 b2 = *(const float2*)&bnB[c0];
    size_t ib = (size_t)i * DIM;
    float2 xi = *(const float2*)&xin[ib + c0];
    float o0 = fmaxf(xi.x + fmaf(acc0, s2.x, b2.x), 0.f);
    float o1 = fmaxf(xi.y + fmaf(acc1, s2.y, b2.y), 0.f);
    if (xout) *(float2*)&xout[ib + c0] = make_float2(o0, o1);
    ushort_t h0 = f2bf(o0), h1 = f2bf(o1);
    *(uint_t*)(A2out + (size_t)i * 512 + c0) = (uint_t)h0 | ((uint_t)h1 << 16);
}

// ---------------- GCN aggregation (batch 32, depth-8 prefetch, bf16 in/out) ----------------
__global__ __launch_bounds__(128) void k_gcn_aggr(
    const ushort_t* __restrict__ h, const float* __restrict__ dinv,
    const float* __restrict__ bias,
    const int* __restrict__ offs, const int* __restrict__ srcH,
    const float* __restrict__ dinvArr, ushort_t* __restrict__ A2out)
{
    int i = blockIdx.x;
    int t = threadIdx.x;
    int c0 = 2 * t;
    float acc0 = 0.f, acc1 = 0.f;
    int e0 = offs[i], e1 = offs[i + 1];
    __shared__ int sS[40];
    __shared__ float sD[40];
    const char* hb = (const char*)(h + c0);  // thread-constant base (4 B / thread)
    for (int base = e0; base < e1; base += 32) {
        int g = min(32, e1 - base);
        __syncthreads();
        if (t < 40) {
            bool ok = (t < g);
            sS[t] = ok ? srcH[base + t] : 0;
            sD[t] = ok ? dinvArr[base + t] : 0.f;
        }
        __syncthreads();
        uint_t q[8];
#pragma unroll
        for (int p = 0; p < 8; p++) q[p] = *(const uint_t*)(hb + (uint_t)sS[p]);
        int j = 0;
        for (; j + 8 <= g; j += 8) {
#pragma unroll
            for (int u = 0; u < 8; u++) {
                uint_t cur = q[u];
                q[u] = *(const uint_t*)(hb + (uint_t)sS[j + u + 8]);
                float d = sD[j + u];
                acc0 = fmaf(d, bflo(cur), acc0);
                acc1 = fmaf(d, bfhi(cur), acc1);
            }
        }
#pragma unroll
        for (int u = 0; u < 7; u++) {
            if (j + u < g) {
                uint_t cur = q[u];
                float d = sD[j + u];
                acc0 = fmaf(d, bflo(cur), acc0);
                acc1 = fmaf(d, bfhi(cur), acc1);
            }
        }
    }
    float di = dinv[i];
    uint_t qi = *(const uint_t*)(h + (size_t)i * HDIM + c0);
    float2 b2 = *(const float2*)&bias[c0];
    float o0 = fmaxf(di * acc0 + di * di * bflo(qi) + b2.x, 0.f);
    float o1 = fmaxf(di * acc1 + di * di * bfhi(qi) + b2.y, 0.f);
    ushort_t h0 = f2bf(o0), h1 = f2bf(o1);
    *(uint_t*)(A2out + (size_t)i * 256 + c0) = (uint_t)h0 | ((uint_t)h1 << 16);
}

// ---------------- launch ----------------
extern "C" void kernel_launch(void* const* d_in, const int* in_sizes, int n_in,
                              void* d_out, int out_size, void* d_ws, size_t ws_size,
                              hipStream_t stream) {
    (void)in_sizes; (void)n_in; (void)out_size; (void)ws_size;
    const float* x      = (const float*)d_in[0];
    const float* ea     = (const float*)d_in[1];
    const float* goal   = (const float*)d_in[2];
    const float* cgWf[2] = {(const float*)d_in[3],  (const float*)d_in[11]};
    const float* cgbf[2] = {(const float*)d_in[4],  (const float*)d_in[12]};
    const float* cgWs[2] = {(const float*)d_in[5],  (const float*)d_in[13]};
    const float* cgbs[2] = {(const float*)d_in[6],  (const float*)d_in[14]};
    const float* cggm[2] = {(const float*)d_in[7],  (const float*)d_in[15]};
    const float* cgbt[2] = {(const float*)d_in[8],  (const float*)d_in[16]};
    const float* cgmn[2] = {(const float*)d_in[9],  (const float*)d_in[17]};
    const float* cgvr[2] = {(const float*)d_in[10], (const float*)d_in[18]};
    const float* gcn3_W = (const float*)d_in[19];
    const float* gcn3_b = (const float*)d_in[20];
    const float* gcn4_W = (const float*)d_in[21];
    const float* gcn4_b = (const float*)d_in[22];
    const float* d1_W   = (const float*)d_in[23];
    const float* d1_b   = (const float*)d_in[24];
    const float* d2_W   = (const float*)d_in[25];
    const float* d2_b   = (const float*)d_in[26];
    const int*   eidx   = (const int*)d_in[27];
    const int*   srcv   = eidx;
    const int*   dstv   = eidx + N_EDGES;
    float* outp = (float*)d_out;

    // ---- workspace layout (~109 MB) ----
    char* w = (char*)d_ws;
    float*    Pbuf  = (float*)w;                      w += (size_t)N_NODES * 1024 * 4;
    ushort_t* Qbuf  = (ushort_t*)w;                   w += (size_t)N_NODES * 1024 * 2;
    float*    xB    = (float*)w;                      w += (size_t)N_NODES * 512 * 4;
    ushort_t* A2    = (ushort_t*)w;                   w += (size_t)N_NODES * 512 * 2;
    ushort_t* A3    = (ushort_t*)w;                   w += (size_t)N_NODES * 256 * 2;
    ushort_t* W2cg0 = (ushort_t*)w;                   w += (size_t)2048 * 512 * 2;
    ushort_t* W2cg1 = (ushort_t*)w;                   w += (size_t)2048 * 512 * 2;
    ushort_t* W2g3  = (ushort_t*)w;                   w += (size_t)256 * 512 * 2;
    ushort_t* W2g4  = (ushort_t*)w;                   w += (size_t)256 * 256 * 2;
    ushort_t* W2d1  = (ushort_t*)w;                   w += (size_t)512 * 256 * 2;
    uint_t*   eaP   = (uint_t*)w;                     w += (size_t)N_EDGES * 8 * 4;
    uint_t*   WB    = (uint_t*)w;                     w += 16384 * 4;
    float*    cgv   = (float*)w;                      w += 512 * 4;
    float*    biasCG = (float*)w;                     w += 2048 * 4;
    float*    bnS    = (float*)w;                     w += 1024 * 4;
    float*    bnB    = (float*)w;                     w += 1024 * 4;
    int*      srcQ    = (int*)w;                      w += N_EDGES * 4;
    int*      srcH    = (int*)w;                      w += N_EDGES * 4;
    float*    dinvArr = (float*)w;                    w += N_EDGES * 4;
    int*      offs    = (int*)w;                      w += (N_NODES + 1) * 4;
    int*      cursor  = (int*)w;                      w += N_NODES * 4;
    float*    dinv    = (float*)w;                    w += N_NODES * 4;
    ushort_t* h3 = (ushort_t*)Pbuf;          // N x 256 bf16

    // ---- prep ----
    k_cvtW<<<592, 256, 0, stream>>>(cgWf[0], cgWs[0], cgWf[1], cgWs[1],
                                    gcn3_W, gcn4_W, d1_W,
                                    W2cg0, W2cg1, W2g3, W2g4, W2d1);
    k_prep2<<<2, 256, 0, stream>>>(cgbf[0], cgbs[0], cggm[0], cgbt[0], cgmn[0], cgvr[0],
                                   cgbf[1], cgbs[1], cggm[1], cgbt[1], cgmn[1], cgvr[1],
                                   biasCG, bnS, bnB);
    k_megaprep<<<MP_END, 256, 0, stream>>>(x, goal,
        cgWf[0], cgWs[0], cgWf[1], cgWs[1], d1_W, d1_b, A2, WB, cgv);

    // ---- CSR build ----
    hipMemsetAsync(offs, 0, (N_NODES + 1) * sizeof(int), stream);
    hipMemsetAsync(cursor, 0, N_NODES * sizeof(int), stream);
    k_hist<<<(N_EDGES + 255) / 256, 256, 0, stream>>>(dstv, offs);
    k_scan<<<1, 1024, 0, stream>>>(offs, dinv);
    k_scatter<<<(N_EDGES + 255) / 256, 256, 0, stream>>>(srcv, dstv, ea, offs, dinv,
                                                         cursor, srcQ, srcH, dinvArr, eaP);

    // ---- CG layer 1 ----
    k_gemm3<<<79 * 16, 256, 0, stream>>>(A2, 512, N_NODES, W2cg0,
                                         Pbuf, Qbuf, biasCG, 1, 0, 79, 16);
    k_cg_aggr<<<N_NODES, 256, 0, stream>>>(x, Pbuf, Qbuf, WB,
                                           bnS, bnB, offs, srcQ, eaP, xB, A2);
    // ---- CG layer 2 (fp32 xout not needed downstream) ----
    k_gemm3<<<79 * 16, 256, 0, stream>>>(A2, 512, N_NODES, W2cg1,
                                         Pbuf, Qbuf, biasCG + 1024, 1, 0, 79, 16);
    k_cg_aggr<<<N_NODES, 256, 0, stream>>>(xB, Pbuf, Qbuf, WB + 8192,
                                           bnS + 512, bnB + 512, offs, srcQ, eaP,
                                           nullptr, A2);

    // ---- GCN 3: 512 -> 256 ----
    k_gemm64<<<157 * 2, 256, 0, stream>>>(A2, 512, N_NODES, W2g3,
                                          nullptr, h3, nullptr, 3, HDIM, 157, 2,
                                          nullptr, nullptr);
    k_gcn_aggr<<<N_NODES, 128, 0, stream>>>(h3, dinv, gcn3_b, offs, srcH, dinvArr, A3);

    // ---- GCN 4: 256 -> 256 ----
    k_gemm64<<<157 * 2, 256, 0, stream>>>(A3, 256, N_NODES, W2g4,
                                          nullptr, h3, nullptr, 3, HDIM, 157, 2,
                                          nullptr, nullptr);
    k_gcn_aggr<<<N_NODES, 128, 0, stream>>>(h3, dinv, gcn4_b, offs, srcH, dinvArr, A3);

    // ---- dense head fused with final dot ----
    hipMemsetAsync(outp, 0, N_NODES * sizeof(float), stream);
    k_gemm64<<<157 * 4, 256, 0, stream>>>(A3, 256, N_NODES, W2d1,
                                          outp, nullptr, cgv, 4, DIM, 157, 4,
                                          d2_W, d2_b);
}